// Round 4
// baseline (459.232 us; speedup 1.0000x reference)
//
#include <hip/hip_runtime.h>
#include <stdint.h>

#define S 1024
#define D 64
#define TQ 16
#define NEG (-1e15f)
#define SCALE 0.125f

#define WB_STRIDE 1048   // bf16 elems; 2096 B row; 524 dwords (mod 32 = 12) -> even bank spread
#define QS_STRIDE 72

typedef __bf16 bf16x8 __attribute__((ext_vector_type(8)));
typedef float f32x4 __attribute__((ext_vector_type(4)));
typedef unsigned short ushort_t;

__device__ __forceinline__ unsigned short f2b(float f) {
  union { float f; uint32_t u; } c; c.f = f;
  uint32_t u = c.u;
  return (unsigned short)((u + 0x7fffu + ((u >> 16) & 1u)) >> 16);  // RNE
}
__device__ __forceinline__ float b2f(uint32_t u) {
  union { uint32_t u; float f; } c; c.u = u << 16;
  return c.f;
}

// ---- prep 1: K fp32 -> bf16, straight layout [bh][j][d] ----
__global__ __launch_bounds__(256) void prep_k_kernel(
    const float* __restrict__ Kg, ushort_t* __restrict__ Kb)
{
  const size_t idx = ((size_t)blockIdx.x * 256 + threadIdx.x) * 8;
  float4 a = *(const float4*)(Kg + idx);
  float4 b = *(const float4*)(Kg + idx + 4);
  ushort_t tmp[8];
  tmp[0]=f2b(a.x); tmp[1]=f2b(a.y); tmp[2]=f2b(a.z); tmp[3]=f2b(a.w);
  tmp[4]=f2b(b.x); tmp[5]=f2b(b.y); tmp[6]=f2b(b.z); tmp[7]=f2b(b.w);
  *(uint4*)(Kb + idx) = *(const uint4*)tmp;
}

// ---- prep 2: V fp32 [bh][j][d] -> bf16 transposed Vt [bh][d][j] ----
__global__ __launch_bounds__(256) void prep_vt_kernel(
    const float* __restrict__ Vg, ushort_t* __restrict__ Vt)
{
  __shared__ __align__(16) ushort_t lvt[D * QS_STRIDE];  // [d][j-in-tile], pad 72
  const int t = threadIdx.x;
  const int bh = blockIdx.x >> 4;
  const int j0 = (blockIdx.x & 15) << 6;

  {  // read 64j x 64d fp32, convert, scatter into lvt[d][j]
    const int j = t >> 2, sd = (t & 3) << 4;
    const float* src = Vg + ((size_t)bh * S + j0 + j) * D + sd;
#pragma unroll
    for (int c = 0; c < 4; ++c) {
      float4 f = *(const float4*)(src + (c << 2));
      lvt[(sd + (c << 2) + 0) * QS_STRIDE + j] = f2b(f.x);
      lvt[(sd + (c << 2) + 1) * QS_STRIDE + j] = f2b(f.y);
      lvt[(sd + (c << 2) + 2) * QS_STRIDE + j] = f2b(f.z);
      lvt[(sd + (c << 2) + 3) * QS_STRIDE + j] = f2b(f.w);
    }
  }
  __syncthreads();
  {  // write rows of Vt coalesced
    const int d = t >> 2, sj = (t & 3) << 4;
    ushort_t tmp[16];
#pragma unroll
    for (int c = 0; c < 4; ++c)
      *(ushort4*)&tmp[c << 2] = *(const ushort4*)&lvt[d * QS_STRIDE + sj + (c << 2)];
    ushort_t* dst = Vt + ((size_t)bh * D + d) * S + j0 + sj;
    *(uint4*)dst = *(const uint4*)&tmp[0];
    *(uint4*)(dst + 8) = *(const uint4*)&tmp[8];
  }
}

__global__ __launch_bounds__(512, 8) void attn_kernel(
    const float* __restrict__ Qg, const ushort_t* __restrict__ Kb,
    const ushort_t* __restrict__ Vtb, const int* __restrict__ PADg,
    float* __restrict__ OCTX, float* __restrict__ OW)
{
  __shared__ __align__(16) ushort_t wb[TQ * WB_STRIDE];   // 33536 B  scores/weights
  __shared__ __align__(16) float pbuf[4 * 16 * 20];       //  5120 B  PV j-half partials

  const int t  = threadIdx.x;
  const int w  = t >> 6;
  const int l  = t & 63;
  const int la = l & 15;
  const int lb = l >> 4;
  const int blk = blockIdx.x;
  const int bh  = blk >> 6;     // 64 consecutive blocks share one head (L2 reuse)
  const int qt  = blk & 63;
  const int qr0 = qt << 4;

  const size_t head = (size_t)bh * S * D;          // element offset (fp32 or bf16 idx)
  const int* pp = PADg + (size_t)(bh >> 4) * S;    // b = bh / H

  // ---- Q A-frags direct from global: A[m=la][k=lb*8+j], two k-halves of D=64
  bf16x8 aq0, aq1;
  {
    const float* qrow = Qg + head + (size_t)(qr0 + la) * D + (lb << 3);
    float4 q00 = *(const float4*)(qrow);
    float4 q01 = *(const float4*)(qrow + 4);
    float4 q10 = *(const float4*)(qrow + 32);
    float4 q11 = *(const float4*)(qrow + 36);
    ushort_t a0[8], a1[8];
    a0[0]=f2b(q00.x); a0[1]=f2b(q00.y); a0[2]=f2b(q00.z); a0[3]=f2b(q00.w);
    a0[4]=f2b(q01.x); a0[5]=f2b(q01.y); a0[6]=f2b(q01.z); a0[7]=f2b(q01.w);
    a1[0]=f2b(q10.x); a1[1]=f2b(q10.y); a1[2]=f2b(q10.z); a1[3]=f2b(q10.w);
    a1[4]=f2b(q11.x); a1[5]=f2b(q11.y); a1[6]=f2b(q11.z); a1[7]=f2b(q11.w);
    aq0 = *(const bf16x8*)a0;
    aq1 = *(const bf16x8*)a1;
  }

  // ---- Phase 1: QK^T, B-frags straight from global (L2-hot), no staging ----
  // wave w owns keys [w*128, w*128+128): 8 subtiles of 16 keys, 2 MFMAs each.
  {
    const ushort_t* kbase = Kb + head;
#pragma unroll
    for (int s = 0; s < 8; ++s) {
      const int j0 = (w << 7) + (s << 4);
      const ushort_t* krow = kbase + (size_t)(j0 + la) * D + (lb << 3);
      f32x4 acc = {0.f, 0.f, 0.f, 0.f};
      bf16x8 b0 = *(const bf16x8*)(krow);
      bf16x8 b1 = *(const bf16x8*)(krow + 32);
      acc = __builtin_amdgcn_mfma_f32_16x16x32_bf16(aq0, b0, acc, 0, 0, 0);
      acc = __builtin_amdgcn_mfma_f32_16x16x32_bf16(aq1, b1, acc, 0, 0, 0);
#pragma unroll
      for (int i = 0; i < 4; ++i)             // D: row=(lb*4+i)=q, col=la=key
        wb[((lb << 2) + i) * WB_STRIDE + j0 + la] = f2b(acc[i]);
    }
  }
  __syncthreads();

  // ---- Phase 2: fp32 softmax (2 rows/wave), float4 lanes, in-place wb + global ----
#pragma unroll
  for (int rr = 0; rr < 2; ++rr) {
    const int r  = (w << 1) + rr;
    const int qr = qr0 + r;
    float lg[16];
    float m = -3.0e38f;
#pragma unroll
    for (int ii = 0; ii < 4; ++ii) {
      const int j = (l << 2) + (ii << 8);
      uint2 pr = *(const uint2*)&wb[r * WB_STRIDE + j];
      int4 pv = *(const int4*)&pp[j];
      float l0 = b2f(pr.x & 0xffffu) * SCALE + (pv.x ? NEG : 0.0f) + ((j     > qr) ? NEG : 0.0f);
      float l1 = b2f(pr.x >> 16)     * SCALE + (pv.y ? NEG : 0.0f) + ((j + 1 > qr) ? NEG : 0.0f);
      float l2 = b2f(pr.y & 0xffffu) * SCALE + (pv.z ? NEG : 0.0f) + ((j + 2 > qr) ? NEG : 0.0f);
      float l3 = b2f(pr.y >> 16)     * SCALE + (pv.w ? NEG : 0.0f) + ((j + 3 > qr) ? NEG : 0.0f);
      lg[4*ii] = l0; lg[4*ii+1] = l1; lg[4*ii+2] = l2; lg[4*ii+3] = l3;
      m = fmaxf(m, fmaxf(fmaxf(l0, l1), fmaxf(l2, l3)));
    }
#pragma unroll
    for (int off = 32; off > 0; off >>= 1) m = fmaxf(m, __shfl_xor(m, off, 64));
    float sum = 0.f;
#pragma unroll
    for (int x = 0; x < 16; ++x) { lg[x] = __expf(lg[x] - m); sum += lg[x]; }
#pragma unroll
    for (int off = 32; off > 0; off >>= 1) sum += __shfl_xor(sum, off, 64);
    const float inv = 1.0f / sum;
    float* orow = OW + (size_t)(bh * S + qr) * S;
#pragma unroll
    for (int ii = 0; ii < 4; ++ii) {
      const int j = (l << 2) + (ii << 8);
      float w0 = lg[4*ii] * inv, w1 = lg[4*ii+1] * inv;
      float w2 = lg[4*ii+2] * inv, w3 = lg[4*ii+3] * inv;
      uint2 pk;
      pk.x = ((uint32_t)f2b(w1) << 16) | (uint32_t)f2b(w0);
      pk.y = ((uint32_t)f2b(w3) << 16) | (uint32_t)f2b(w2);
      *(uint2*)&wb[r * WB_STRIDE + j] = pk;
      *(float4*)&orow[j] = make_float4(w0, w1, w2, w3);
    }
  }
  __syncthreads();

  // ---- Phase 3: PV, Vt B-frags straight from global. wave -> (d0=(w&3)*16, j-half=w>>2)
  const int jh = w >> 2;
  const int d0 = (w & 3) << 4;
  f32x4 cacc = {0.f, 0.f, 0.f, 0.f};
  {
    const ushort_t* vbase = Vtb + (size_t)bh * D * S + (size_t)(d0 + la) * S;
#pragma unroll
    for (int ks = 0; ks < 16; ++ks) {
      const int jt = (jh << 9) + (ks << 5);
      bf16x8 af = *(const bf16x8*)&wb[la * WB_STRIDE + jt + (lb << 3)];
      bf16x8 bf = *(const bf16x8*)(vbase + jt + (lb << 3));
      cacc = __builtin_amdgcn_mfma_f32_16x16x32_bf16(af, bf, cacc, 0, 0, 0);
    }
  }

  // ---- Phase 4: reduce the two j-halves, store context ----
  if (w >= 4) {
#pragma unroll
    for (int i = 0; i < 4; ++i)
      pbuf[(w - 4) * 320 + ((lb << 2) + i) * 20 + la] = cacc[i];
  }
  __syncthreads();
  if (w < 4) {
#pragma unroll
    for (int i = 0; i < 4; ++i) {
      const int qrow = (lb << 2) + i;
      OCTX[((size_t)(bh * S) + qr0 + qrow) * D + d0 + la] =
          cacc[i] + pbuf[w * 320 + qrow * 20 + la];
    }
  }
}

extern "C" void kernel_launch(void* const* d_in, const int* in_sizes, int n_in,
                              void* d_out, int out_size, void* d_ws, size_t ws_size,
                              hipStream_t stream) {
  const float* q   = (const float*)d_in[0];
  const float* k   = (const float*)d_in[1];
  const float* v   = (const float*)d_in[2];
  const int*   pad = (const int*)d_in[3];
  // d_in[4] (look_ahead_mask) is reproduced analytically from indices.
  float* ctx  = (float*)d_out;
  float* wout = (float*)d_out + (size_t)4 * 16 * S * D;   // weights after context

  ushort_t* Kb  = (ushort_t*)d_ws;                          // 8 MB bf16 K
  ushort_t* Vtb = (ushort_t*)d_ws + (size_t)4 * 16 * S * D; // 8 MB bf16 V^T

  prep_k_kernel <<<dim3(2048), dim3(256), 0, stream>>>(k, Kb);
  prep_vt_kernel<<<dim3(1024), dim3(256), 0, stream>>>(v, Vtb);
  attn_kernel   <<<dim3(4096), dim3(512), 0, stream>>>(q, Kb, Vtb, pad, ctx, wout);
}